// Round 1
// baseline (3893.442 us; speedup 1.0000x reference)
//
#include <hip/hip_runtime.h>
#include <hip/hip_bf16.h>

typedef unsigned short u16;
typedef unsigned int u32;

__device__ __forceinline__ float bf2f(u16 h) {
    return __uint_as_float(((u32)h) << 16);
}
__device__ __forceinline__ u16 f2bf(float f) {
    __hip_bfloat16 h = __float2bfloat16(f);   // RNE
    return *reinterpret_cast<u16*>(&h);
}

#define MEGA_GRID 768          // 256 CU x 3 blocks/CU (LDS-limited, see launch_bounds)
#define SPMM_ROWS 32
#define SPMM_LDSE 2048
// smem layout: As[64*132]f @0 (33792B) | Bs[64*64]f @33792 (16384B) | sums[128]f @50176 (512B)
#define MEGA_LDS  50688

// ---- device-wide barrier: monotonic counter, agent-scope acq/rel ----
// Release (buffer_wbl2) flushes this XCD's dirty L2 lines; acquire (buffer_inv)
// invalidates stale L1/L2 — required across non-coherent per-XCD L2s.
__device__ __forceinline__ void grid_bar(int* bar, int epoch) {
    __syncthreads();    // drains this block's outstanding vmem (vmcnt(0) before s_barrier)
    if (threadIdx.x == 0) {
        __hip_atomic_fetch_add(bar, 1, __ATOMIC_ACQ_REL, __HIP_MEMORY_SCOPE_AGENT);
        const int tgt = epoch * (int)gridDim.x;
        while (__hip_atomic_load(bar, __ATOMIC_ACQUIRE, __HIP_MEMORY_SCOPE_AGENT) < tgt)
            __builtin_amdgcn_s_sleep(4);
    }
    __syncthreads();
}

// ---- phase: single-block exclusive scan of cnt -> rowptr/cursor/dis ----
__device__ void scan_phase(char* smem, const int* __restrict__ cnt,
                           int* __restrict__ rowptr, int* __restrict__ cursor,
                           float* __restrict__ dis, int n)
{
    if (blockIdx.x != 0) return;
    int* sc = (int*)smem;
    const int per = (n + 255) / 256;
    const int s = threadIdx.x * per;
    const int e = min(n, s + per);
    int lsum = 0;
    for (int i = s; i < e; ++i) lsum += cnt[i];
    sc[threadIdx.x] = lsum;
    __syncthreads();
    #pragma unroll
    for (int off = 1; off < 256; off <<= 1) {
        int t = (threadIdx.x >= off) ? sc[threadIdx.x - off] : 0;
        __syncthreads();
        sc[threadIdx.x] += t;
        __syncthreads();
    }
    int run = sc[threadIdx.x] - lsum;   // exclusive prefix
    for (int i = s; i < e; ++i) {
        int c = cnt[i];
        rowptr[i] = run;
        cursor[i] = run;
        dis[i] = (c > 0) ? rsqrtf((float)c) : 0.0f;
        run += c;
    }
    if (threadIdx.x == 255) rowptr[n] = run;   // == E
}

// ---- phase: CSR SpMM (tilde form), grid-strided over 32-row groups ----
__device__ void spmm_phase(char* smem,
    const u16* __restrict__ in, const u16* __restrict__ addsrc,
    u16* __restrict__ out1, u16* __restrict__ out2,
    const int* __restrict__ rowptr, const u32* __restrict__ ecol,
    const float* __restrict__ dis, const float* __restrict__ b,
    int relu, int sq1, int n)
{
    u32* eld = (u32*)smem;
    const int ngroups = (n + SPMM_ROWS - 1) / SPMM_ROWS;
    const int lr = threadIdx.x >> 3;
    const int q  = threadIdx.x & 7;
    for (int g = blockIdx.x; g < ngroups; g += gridDim.x) {
        const int r0 = g * SPMM_ROWS;
        const int rend = min(n, r0 + SPMM_ROWS);
        const int estart = rowptr[r0];
        const int eendb  = rowptr[rend];
        const int ne = eendb - estart;
        const bool lds_ok = (ne <= SPMM_LDSE);
        if (lds_ok) {
            for (int j = threadIdx.x; j < ne; j += 256)
                eld[j] = ecol[estart + j];
        }
        __syncthreads();
        const int r = r0 + lr;
        if (r < n) {
            int e0 = rowptr[r], e1 = rowptr[r + 1];
            float ax0=0,ay0=0, ax1=0,ay1=0, ax2=0,ay2=0, ax3=0,ay3=0;
            if (lds_ok) {
                int le = e0 - estart, le1 = e1 - estart;
                for (; le + 4 <= le1; le += 4) {
                    u32 s0 = eld[le], s1 = eld[le+1], s2 = eld[le+2], s3 = eld[le+3];
                    ushort2 v0 = *((const ushort2*)(in + (size_t)s0 * 16) + q);
                    ushort2 v1 = *((const ushort2*)(in + (size_t)s1 * 16) + q);
                    ushort2 v2 = *((const ushort2*)(in + (size_t)s2 * 16) + q);
                    ushort2 v3 = *((const ushort2*)(in + (size_t)s3 * 16) + q);
                    ax0 += bf2f(v0.x); ay0 += bf2f(v0.y);
                    ax1 += bf2f(v1.x); ay1 += bf2f(v1.y);
                    ax2 += bf2f(v2.x); ay2 += bf2f(v2.y);
                    ax3 += bf2f(v3.x); ay3 += bf2f(v3.y);
                }
                for (; le < le1; ++le) {
                    ushort2 v0 = *((const ushort2*)(in + (size_t)eld[le] * 16) + q);
                    ax0 += bf2f(v0.x); ay0 += bf2f(v0.y);
                }
            } else {
                int e = e0;
                for (; e + 4 <= e1; e += 4) {
                    u32 s0 = ecol[e], s1 = ecol[e+1], s2 = ecol[e+2], s3 = ecol[e+3];
                    ushort2 v0 = *((const ushort2*)(in + (size_t)s0 * 16) + q);
                    ushort2 v1 = *((const ushort2*)(in + (size_t)s1 * 16) + q);
                    ushort2 v2 = *((const ushort2*)(in + (size_t)s2 * 16) + q);
                    ushort2 v3 = *((const ushort2*)(in + (size_t)s3 * 16) + q);
                    ax0 += bf2f(v0.x); ay0 += bf2f(v0.y);
                    ax1 += bf2f(v1.x); ay1 += bf2f(v1.y);
                    ax2 += bf2f(v2.x); ay2 += bf2f(v2.y);
                    ax3 += bf2f(v3.x); ay3 += bf2f(v3.y);
                }
                for (; e < e1; ++e) {
                    ushort2 v0 = *((const ushort2*)(in + (size_t)ecol[e] * 16) + q);
                    ax0 += bf2f(v0.x); ay0 += bf2f(v0.y);
                }
            }
            float Sx = (ax0 + ax1) + (ax2 + ax3);
            float Sy = (ay0 + ay1) + (ay2 + ay3);
            float d1 = dis[r];
            float sc1 = sq1 ? d1 * d1 : d1;
            float Ax = Sx * sc1, Ay = Sy * sc1;
            if (addsrc) {
                ushort2 s = *((const ushort2*)(addsrc + (size_t)r * 16) + q);
                Ax += bf2f(s.x); Ay += bf2f(s.y);
            }
            if (b) {
                Ax += b[2 * q];
                Ay += b[2 * q + 1];
            }
            if (relu) {
                Ax = fmaxf(Ax, 0.f);
                Ay = fmaxf(Ay, 0.f);
            }
            ushort2 o; o.x = f2bf(Ax); o.y = f2bf(Ay);
            *((ushort2*)(out1 + (size_t)r * 16) + q) = o;
            if (out2) {
                ushort2 o2; o2.x = f2bf(Ax * d1); o2.y = f2bf(Ay * d1);
                *((ushort2*)(out2 + (size_t)r * 16) + q) = o2;
            }
        }
        __syncthreads();   // WAR: protect eld before next group restage
    }
}

// ---- phase: GEMM1 (x @ W1 planes, row-normalize, tilde-scale planes 1..3) ----
__device__ void gemm1_phase(char* smem, const float* __restrict__ x,
                            const float* __restrict__ W1,
                            const float* __restrict__ dis,
                            u16* __restrict__ zb, int n, int nstride)
{
    float* As   = (float*)smem;
    float* Bs   = (float*)(smem + 33792);
    float* sums = (float*)(smem + 50176);
    const int t  = threadIdx.x;
    const int tx = t & 15;
    const int ty = t >> 4;
    const int c  = t & 15;
    const int g  = t >> 4;
    const int ntiles = (n + 127) >> 7;
    for (int tile = blockIdx.x; tile < ntiles; tile += gridDim.x) {
        const int block_row = tile << 7;
        float acc[8][4];
        #pragma unroll
        for (int i = 0; i < 8; ++i)
            #pragma unroll
            for (int j = 0; j < 4; ++j) acc[i][j] = 0.f;

        for (int kp = 0; kp < 2; ++kp) {
            #pragma unroll
            for (int i = 0; i < 8; ++i) {
                int row  = g + 16 * i;
                int grow = block_row + row;
                float v0 = 0.f, v1 = 0.f, v2 = 0.f, v3 = 0.f;
                if (grow < n) {
                    const float* xp = x + (long)grow * 128 + kp * 64 + c;
                    v0 = xp[0]; v1 = xp[16]; v2 = xp[32]; v3 = xp[48];
                }
                As[(c +  0) * 132 + row] = v0;
                As[(c + 16) * 132 + row] = v1;
                As[(c + 32) * 132 + row] = v2;
                As[(c + 48) * 132 + row] = v3;
                float red = (v0 + v1) + (v2 + v3);
                #pragma unroll
                for (int off = 8; off > 0; off >>= 1) red += __shfl_down(red, off, 16);
                if (c == 0) { if (kp == 0) sums[row] = red; else sums[row] += red; }
            }
            #pragma unroll
            for (int i2 = 0; i2 < 4; ++i2) {
                int kk = g + 16 * i2;
                int kglob = kp * 64 + kk;
                float4 wv = *(const float4*)(W1 + (c >> 2) * 2048 + kglob * 16 + 4 * (c & 3));
                *(float4*)(Bs + kk * 64 + 4 * c) = wv;
            }
            __syncthreads();
            #pragma unroll 4
            for (int kk = 0; kk < 64; ++kk) {
                float4 a0 = *(const float4*)(As + kk * 132 + 8 * ty);
                float4 a1 = *(const float4*)(As + kk * 132 + 8 * ty + 4);
                float4 bv = *(const float4*)(Bs + kk * 64 + 4 * tx);
                float ar[8] = {a0.x, a0.y, a0.z, a0.w, a1.x, a1.y, a1.z, a1.w};
                float br[4] = {bv.x, bv.y, bv.z, bv.w};
                #pragma unroll
                for (int i = 0; i < 8; ++i)
                    #pragma unroll
                    for (int j = 0; j < 4; ++j)
                        acc[i][j] += ar[i] * br[j];
            }
            __syncthreads();
        }
        int plane = tx >> 2;
        int oo4   = 4 * (tx & 3);
        #pragma unroll
        for (int i = 0; i < 8; ++i) {
            int row  = 8 * ty + i;
            int grow = block_row + row;
            if (grow < n) {
                float s = 1.0f / fmaxf(sums[row], 1e-8f);
                if (plane != 0) s *= dis[grow];          // tilde space for SpMM inputs
                ushort4 o;
                o.x = f2bf(acc[i][0] * s); o.y = f2bf(acc[i][1] * s);
                o.z = f2bf(acc[i][2] * s); o.w = f2bf(acc[i][3] * s);
                *(ushort4*)(zb + (long)plane * nstride + (long)grow * 16 + oo4) = o;
            }
        }
        __syncthreads();
    }
}

// ---- phase: GEMM2 (cat(P0..P3) @ W2cat + b2 -> fp32 out) ----
__device__ void gemm2_phase(char* smem, const u16* __restrict__ zb,
                            const float* __restrict__ W2,
                            const float* __restrict__ b2,
                            float* __restrict__ out, int n, int nstride)
{
    float* As = (float*)smem;
    float* Bs = (float*)(smem + 33792);
    const int t  = threadIdx.x;
    const int tx = t & 15;
    const int ty = t >> 4;
    const int c  = t & 15;
    const int g  = t >> 4;
    const int ntiles = (n + 127) >> 7;
    for (int tile = blockIdx.x; tile < ntiles; tile += gridDim.x) {
        const int block_row = tile << 7;
        float acc[8][4];
        #pragma unroll
        for (int i = 0; i < 8; ++i)
            #pragma unroll
            for (int j = 0; j < 4; ++j) acc[i][j] = 0.f;

        #pragma unroll
        for (int i = 0; i < 8; ++i) {
            int row  = g + 16 * i;
            int grow = block_row + row;
            float v0 = 0.f, v1 = 0.f, v2 = 0.f, v3 = 0.f;
            if (grow < n) {
                const u16* zp = zb + (long)grow * 16 + c;
                v0 = bf2f(zp[0]);
                v1 = bf2f(zp[(long)nstride]);
                v2 = bf2f(zp[2 * (long)nstride]);
                v3 = bf2f(zp[3 * (long)nstride]);
            }
            As[(c +  0) * 132 + row] = v0;
            As[(c + 16) * 132 + row] = v1;
            As[(c + 32) * 132 + row] = v2;
            As[(c + 48) * 132 + row] = v3;
        }
        #pragma unroll
        for (int i2 = 0; i2 < 4; ++i2) {
            int j = g + 16 * i2;
            float4 wv = *(const float4*)(W2 + j * 64 + 4 * c);
            *(float4*)(Bs + j * 64 + 4 * c) = wv;
        }
        __syncthreads();
        #pragma unroll 4
        for (int kk = 0; kk < 64; ++kk) {
            float4 a0 = *(const float4*)(As + kk * 132 + 8 * ty);
            float4 a1 = *(const float4*)(As + kk * 132 + 8 * ty + 4);
            float4 bv = *(const float4*)(Bs + kk * 64 + 4 * tx);
            float ar[8] = {a0.x, a0.y, a0.z, a0.w, a1.x, a1.y, a1.z, a1.w};
            float br[4] = {bv.x, bv.y, bv.z, bv.w};
            #pragma unroll
            for (int i = 0; i < 8; ++i)
                #pragma unroll
                for (int j = 0; j < 4; ++j)
                    acc[i][j] += ar[i] * br[j];
        }
        float4 bias = *(const float4*)(b2 + 4 * tx);
        #pragma unroll
        for (int i = 0; i < 8; ++i) {
            int grow = block_row + 8 * ty + i;
            if (grow < n) {
                float4 o = make_float4(acc[i][0] + bias.x, acc[i][1] + bias.y,
                                       acc[i][2] + bias.z, acc[i][3] + bias.w);
                *(float4*)(out + (long)grow * 64 + 4 * tx) = o;
            }
        }
        __syncthreads();
    }
}

// ==================== the persistent mega-kernel ====================
// 768 blocks x 256 thr; LDS 50688 -> exactly 3 blocks/CU; launch_bounds(256,3)
// caps VGPR at 168 so occupancy can't drop below 3/CU => all blocks co-resident.
__global__ __launch_bounds__(256, 3) void mega_kernel(
    const float* __restrict__ x, const int* __restrict__ srcp,
    const int* __restrict__ dstp,
    const float* __restrict__ W1, const float* __restrict__ b1,
    const float* __restrict__ W2, const float* __restrict__ b2,
    float* __restrict__ out,
    int* bar, int* cnt, int* rowptr, int* cursor, float* dis,
    u16* zb, u32* ecol, int n, int E, int nstride)
{
    __shared__ __align__(16) char smem[MEGA_LDS];
    const int gstride = (int)gridDim.x * 256;

    // P1: in-degree count (cnt zeroed by preceding memset)
    for (int e = blockIdx.x * 256 + threadIdx.x; e < E; e += gstride)
        atomicAdd(&cnt[dstp[e]], 1);
    grid_bar(bar, 1);

    // P2: scan -> rowptr / cursor / dis (block 0 only)
    scan_phase(smem, cnt, rowptr, cursor, dis, n);
    grid_bar(bar, 2);

    // P3: scatter edges into CSR via atomic cursors (order within row arbitrary)
    for (int e = blockIdx.x * 256 + threadIdx.x; e < E; e += gstride) {
        int d = dstp[e];
        int p = atomicAdd(&cursor[d], 1);
        ecol[p] = (u32)srcp[e];
    }
    grid_bar(bar, 3);

    // P4: GEMM1 -> P0 (normal), P1..P3 (tilde)
    gemm1_phase(smem, x, W1, dis, zb, n, nstride);
    grid_bar(bar, 4);

    u16 *P0 = zb, *P1 = zb + nstride, *P2 = zb + 2 * nstride, *P3 = zb + 3 * nstride;
    u16 *T0 = zb + 4 * nstride, *T1 = zb + 5 * nstride;

    // L1 Horner (tilde space: scale1 = dis^2)
    spmm_phase(smem, P3, P2, P2, nullptr, rowptr, ecol, dis, nullptr, 0, 1, n);
    grid_bar(bar, 5);
    spmm_phase(smem, P2, P1, P1, nullptr, rowptr, ecol, dis, nullptr, 0, 1, n);
    grid_bar(bar, 6);
    // h1 = relu(z0 + dis*S + b1); T0 = dis*h1
    spmm_phase(smem, P1, P0, P0, T0, rowptr, ecol, dis, b1, 1, 0, n);
    grid_bar(bar, 7);
    // L2 hops: g_k = dis*S (gemm2 input), tilde copy = dis*g_k
    spmm_phase(smem, T0, nullptr, P1, T1, rowptr, ecol, dis, nullptr, 0, 0, n);
    grid_bar(bar, 8);
    spmm_phase(smem, T1, nullptr, P2, T0, rowptr, ecol, dis, nullptr, 0, 0, n);
    grid_bar(bar, 9);
    spmm_phase(smem, T0, nullptr, P3, nullptr, rowptr, ecol, dis, nullptr, 0, 0, n);
    grid_bar(bar, 10);

    // P11: GEMM2 -> out
    gemm2_phase(smem, zb, W2, b2, out, n, nstride);
}

// ================= fp32 fallback path (small workspace) =================
__global__ void deg_kernel(const int* __restrict__ dst, float* __restrict__ deg, int E) {
    int e = blockIdx.x * blockDim.x + threadIdx.x;
    if (e < E) atomicAdd(&deg[dst[e]], 1.0f);
}
__global__ void disf_kernel(float* __restrict__ deg, int n) {
    int i = blockIdx.x * blockDim.x + threadIdx.x;
    if (i < n) {
        float d = deg[i];
        deg[i] = (d > 0.0f) ? rsqrtf(d) : 0.0f;
    }
}
__global__ __launch_bounds__(256) void gemm1_f32_kernel(
    const float* __restrict__ x, const float* __restrict__ W1,
    float* __restrict__ z, int n, int nstride)
{
    __shared__ float As[64 * 132];
    __shared__ float Bs[64 * 64];
    __shared__ float sums[128];
    const int t  = threadIdx.x;
    const int tx = t & 15;
    const int ty = t >> 4;
    const int c  = t & 15;
    const int g  = t >> 4;
    const int block_row = blockIdx.x * 128;
    float acc[8][4];
    #pragma unroll
    for (int i = 0; i < 8; ++i)
        #pragma unroll
        for (int j = 0; j < 4; ++j) acc[i][j] = 0.f;
    for (int kp = 0; kp < 2; ++kp) {
        #pragma unroll
        for (int i = 0; i < 8; ++i) {
            int row  = g + 16 * i;
            int grow = block_row + row;
            float v0 = 0.f, v1 = 0.f, v2 = 0.f, v3 = 0.f;
            if (grow < n) {
                const float* xp = x + (long)grow * 128 + kp * 64 + c;
                v0 = xp[0]; v1 = xp[16]; v2 = xp[32]; v3 = xp[48];
            }
            As[(c +  0) * 132 + row] = v0;
            As[(c + 16) * 132 + row] = v1;
            As[(c + 32) * 132 + row] = v2;
            As[(c + 48) * 132 + row] = v3;
            float red = (v0 + v1) + (v2 + v3);
            #pragma unroll
            for (int off = 8; off > 0; off >>= 1) red += __shfl_down(red, off, 16);
            if (c == 0) { if (kp == 0) sums[row] = red; else sums[row] += red; }
        }
        #pragma unroll
        for (int i2 = 0; i2 < 4; ++i2) {
            int kk = g + 16 * i2;
            int kglob = kp * 64 + kk;
            float4 wv = *(const float4*)(W1 + (c >> 2) * 2048 + kglob * 16 + 4 * (c & 3));
            *(float4*)(Bs + kk * 64 + 4 * c) = wv;
        }
        __syncthreads();
        #pragma unroll 4
        for (int kk = 0; kk < 64; ++kk) {
            float4 a0 = *(const float4*)(As + kk * 132 + 8 * ty);
            float4 a1 = *(const float4*)(As + kk * 132 + 8 * ty + 4);
            float4 bv = *(const float4*)(Bs + kk * 64 + 4 * tx);
            float ar[8] = {a0.x, a0.y, a0.z, a0.w, a1.x, a1.y, a1.z, a1.w};
            float br[4] = {bv.x, bv.y, bv.z, bv.w};
            #pragma unroll
            for (int i = 0; i < 8; ++i)
                #pragma unroll
                for (int j = 0; j < 4; ++j)
                    acc[i][j] += ar[i] * br[j];
        }
        __syncthreads();
    }
    int plane = tx >> 2;
    int oo4   = 4 * (tx & 3);
    #pragma unroll
    for (int i = 0; i < 8; ++i) {
        int row  = 8 * ty + i;
        int grow = block_row + row;
        if (grow < n) {
            float s = 1.0f / fmaxf(sums[row], 1e-8f);
            float4 o = make_float4(acc[i][0] * s, acc[i][1] * s, acc[i][2] * s, acc[i][3] * s);
            *(float4*)(z + (long)plane * nstride + (long)grow * 16 + oo4) = o;
        }
    }
}
__global__ __launch_bounds__(256) void spmm_atomic_kernel(
    const float* __restrict__ in, float* __restrict__ out,
    const int* __restrict__ src, const int* __restrict__ dst,
    const float* __restrict__ dis, int E)
{
    int t = blockIdx.x * blockDim.x + threadIdx.x;
    int e = t >> 4, f = t & 15;
    if (e < E) {
        int s = src[e], d = dst[e];
        atomicAdd(&out[d * 16 + f], dis[s] * dis[d] * in[s * 16 + f]);
    }
}
__global__ void bias_relu_kernel(float* __restrict__ z0, const float* __restrict__ b, int total) {
    int i = blockIdx.x * blockDim.x + threadIdx.x;
    if (i < total) {
        float v = z0[i] + b[i & 15];
        z0[i] = v > 0.0f ? v : 0.0f;
    }
}
__global__ __launch_bounds__(256) void gemm2_f32_kernel(
    const float* __restrict__ z, const float* __restrict__ W2,
    const float* __restrict__ b2, float* __restrict__ out, int n, int nstride)
{
    __shared__ float As[64 * 132];
    __shared__ float Bs[64 * 64];
    const int t  = threadIdx.x;
    const int tx = t & 15;
    const int ty = t >> 4;
    const int c  = t & 15;
    const int g  = t >> 4;
    const int block_row = blockIdx.x * 128;
    float acc[8][4];
    #pragma unroll
    for (int i = 0; i < 8; ++i)
        #pragma unroll
        for (int j = 0; j < 4; ++j) acc[i][j] = 0.f;
    #pragma unroll
    for (int i = 0; i < 8; ++i) {
        int row  = g + 16 * i;
        int grow = block_row + row;
        float v0 = 0.f, v1 = 0.f, v2 = 0.f, v3 = 0.f;
        if (grow < n) {
            const float* zp = z + (long)grow * 16 + c;
            v0 = zp[0];
            v1 = zp[(long)nstride];
            v2 = zp[2 * (long)nstride];
            v3 = zp[3 * (long)nstride];
        }
        As[(c +  0) * 132 + row] = v0;
        As[(c + 16) * 132 + row] = v1;
        As[(c + 32) * 132 + row] = v2;
        As[(c + 48) * 132 + row] = v3;
    }
    #pragma unroll
    for (int i2 = 0; i2 < 4; ++i2) {
        int j = g + 16 * i2;
        float4 wv = *(const float4*)(W2 + j * 64 + 4 * c);
        *(float4*)(Bs + j * 64 + 4 * c) = wv;
    }
    __syncthreads();
    #pragma unroll 4
    for (int kk = 0; kk < 64; ++kk) {
        float4 a0 = *(const float4*)(As + kk * 132 + 8 * ty);
        float4 a1 = *(const float4*)(As + kk * 132 + 8 * ty + 4);
        float4 bv = *(const float4*)(Bs + kk * 64 + 4 * tx);
        float ar[8] = {a0.x, a0.y, a0.z, a0.w, a1.x, a1.y, a1.z, a1.w};
        float br[4] = {bv.x, bv.y, bv.z, bv.w};
        #pragma unroll
        for (int i = 0; i < 8; ++i)
            #pragma unroll
            for (int j = 0; j < 4; ++j)
                acc[i][j] += ar[i] * br[j];
    }
    float4 bias = *(const float4*)(b2 + 4 * tx);
    #pragma unroll
    for (int i = 0; i < 8; ++i) {
        int grow = block_row + 8 * ty + i;
        if (grow < n) {
            float4 o = make_float4(acc[i][0] + bias.x, acc[i][1] + bias.y,
                                   acc[i][2] + bias.z, acc[i][3] + bias.w);
            *(float4*)(out + (long)grow * 64 + 4 * tx) = o;
        }
    }
}

static inline size_t align16(size_t v) { return (v + 15) & ~(size_t)15; }

extern "C" void kernel_launch(void* const* d_in, const int* in_sizes, int n_in,
                              void* d_out, int out_size, void* d_ws, size_t ws_size,
                              hipStream_t stream) {
    const float* x   = (const float*)d_in[0];
    const int*   ei  = (const int*)d_in[1];
    const float* W1  = (const float*)d_in[2];
    const float* b1  = (const float*)d_in[3];
    const float* W2  = (const float*)d_in[4];
    const float* bb2 = (const float*)d_in[5];
    float* out = (float*)d_out;

    const int n  = in_sizes[0] / 128;   // 50000
    const int E  = in_sizes[1] / 2;     // 800000
    const int NS = n * 16;

    const int* srcp = ei;
    const int* dstp = ei + E;

    char* wsb = (char*)d_ws;
    // layout: bar(16B) | cnt[n] | rowptr[n+1] | cursor[n] | dis[n] | zb[6*NS u16] | ecol[E u32]
    int*   bar    = (int*)wsb;
    int*   cnt    = (int*)(wsb + 16);
    int*   rowptr = (int*)(wsb + 16 + (size_t)4 * n);
    int*   cursor = (int*)(wsb + 16 + (size_t)4 * (2 * n + 1));
    float* dis    = (float*)(wsb + 16 + (size_t)4 * (3 * n + 1));
    size_t zoffb  = align16(16 + (size_t)4 * (4 * n + 1));
    u16*   zb     = (u16*)(wsb + zoffb);
    size_t ecooff = align16(zoffb + (size_t)2 * 6 * NS);
    u32*   ecol   = (u32*)(wsb + ecooff);
    size_t need   = ecooff + (size_t)4 * E;

    if (ws_size >= need) {
        // zero bar counter + degree counts, then one persistent kernel for everything
        hipMemsetAsync(wsb, 0, 16 + (size_t)4 * n, stream);
        mega_kernel<<<MEGA_GRID, 256, 0, stream>>>(
            x, srcp, dstp, W1, b1, W2, bb2, out,
            bar, cnt, rowptr, cursor, dis, zb, ecol, n, E, NS);
    } else {
        // ---------- fp32 atomic fallback ----------
        int gemm_blocks = (n + 127) / 128;
        float* ws = (float*)d_ws;
        float* dis2 = ws;
        size_t z2off = ((size_t)n + 3) & ~(size_t)3;
        float* z2 = ws + z2off;
        hipMemsetAsync(dis2, 0, n * sizeof(float), stream);
        deg_kernel<<<(E + 255) / 256, 256, 0, stream>>>(dstp, dis2, E);
        disf_kernel<<<(n + 255) / 256, 256, 0, stream>>>(dis2, n);
        gemm1_f32_kernel<<<gemm_blocks, 256, 0, stream>>>(x, W1, z2, n, NS);
        int sb = (16 * E + 255) / 256;
        spmm_atomic_kernel<<<sb, 256, 0, stream>>>(z2 + 3 * NS, z2 + 2 * NS, srcp, dstp, dis2, E);
        spmm_atomic_kernel<<<sb, 256, 0, stream>>>(z2 + 2 * NS, z2 + 1 * NS, srcp, dstp, dis2, E);
        spmm_atomic_kernel<<<sb, 256, 0, stream>>>(z2 + 1 * NS, z2,          srcp, dstp, dis2, E);
        bias_relu_kernel<<<(NS + 255) / 256, 256, 0, stream>>>(z2, b1, NS);
        hipMemsetAsync(z2 + NS, 0, (size_t)3 * NS * sizeof(float), stream);
        spmm_atomic_kernel<<<sb, 256, 0, stream>>>(z2,          z2 + NS,     srcp, dstp, dis2, E);
        spmm_atomic_kernel<<<sb, 256, 0, stream>>>(z2 + NS,     z2 + 2 * NS, srcp, dstp, dis2, E);
        spmm_atomic_kernel<<<sb, 256, 0, stream>>>(z2 + 2 * NS, z2 + 3 * NS, srcp, dstp, dis2, E);
        gemm2_f32_kernel<<<gemm_blocks, 256, 0, stream>>>(z2, W2, bb2, out, n, NS);
    }
}

// Round 2
// 987.781 us; speedup vs baseline: 3.9416x; 3.9416x over previous
//
#include <hip/hip_runtime.h>
#include <hip/hip_bf16.h>

typedef unsigned short u16;
typedef unsigned int u32;

__device__ __forceinline__ float bf2f(u16 h) {
    return __uint_as_float(((u32)h) << 16);
}
__device__ __forceinline__ u16 f2bf(float f) {
    __hip_bfloat16 h = __float2bfloat16(f);   // RNE
    return *reinterpret_cast<u16*>(&h);
}

#define MEGA_GRID 768          // 256 CU x 3 blocks/CU (LDS-limited, see launch_bounds)
#define SPMM_ROWS 32
#define SPMM_LDSE 2048
// smem layout: As[64*132]f @0 (33792B) | Bs[64*64]f @33792 (16384B) | sums[128]f @50176 (512B)
#define MEGA_LDS  50688

// ---- device-wide barrier ----
// ONE release fence before signaling (flush this XCD's dirty L2), RELAXED polls
// (no per-iteration cache ops!), ONE acquire fence after the count is reached.
// The previous version used ACQUIRE in the spin loop: every poll emitted a full
// L2 invalidate -> ~400us per barrier. This is the fix.
__device__ __forceinline__ void grid_bar(int* bar, int epoch) {
    __syncthreads();    // compiler drains vmcnt/lgkmcnt before s_barrier
    if (threadIdx.x == 0) {
        __builtin_amdgcn_fence(__ATOMIC_RELEASE, "agent");
        __hip_atomic_fetch_add(bar, 1, __ATOMIC_RELAXED, __HIP_MEMORY_SCOPE_AGENT);
        const int tgt = epoch * (int)gridDim.x;
        while (__hip_atomic_load(bar, __ATOMIC_RELAXED, __HIP_MEMORY_SCOPE_AGENT) < tgt)
            __builtin_amdgcn_s_sleep(8);
        __builtin_amdgcn_fence(__ATOMIC_ACQUIRE, "agent");
    }
    __syncthreads();
}

// ---- phase: single-block exclusive scan of cnt -> rowptr/cursor/dis ----
__device__ void scan_phase(char* smem, const int* __restrict__ cnt,
                           int* __restrict__ rowptr, int* __restrict__ cursor,
                           float* __restrict__ dis, int n)
{
    if (blockIdx.x != 0) return;
    int* sc = (int*)smem;
    const int per = (n + 255) / 256;
    const int s = threadIdx.x * per;
    const int e = min(n, s + per);
    int lsum = 0;
    for (int i = s; i < e; ++i) lsum += cnt[i];
    sc[threadIdx.x] = lsum;
    __syncthreads();
    #pragma unroll
    for (int off = 1; off < 256; off <<= 1) {
        int t = (threadIdx.x >= off) ? sc[threadIdx.x - off] : 0;
        __syncthreads();
        sc[threadIdx.x] += t;
        __syncthreads();
    }
    int run = sc[threadIdx.x] - lsum;   // exclusive prefix
    for (int i = s; i < e; ++i) {
        int c = cnt[i];
        rowptr[i] = run;
        cursor[i] = run;
        dis[i] = (c > 0) ? rsqrtf((float)c) : 0.0f;
        run += c;
    }
    if (threadIdx.x == 255) rowptr[n] = run;   // == E
}

// ---- phase: CSR SpMM (tilde form), grid-strided over 32-row groups ----
__device__ void spmm_phase(char* smem,
    const u16* __restrict__ in, const u16* __restrict__ addsrc,
    u16* __restrict__ out1, u16* __restrict__ out2,
    const int* __restrict__ rowptr, const u32* __restrict__ ecol,
    const float* __restrict__ dis, const float* __restrict__ b,
    int relu, int sq1, int n)
{
    u32* eld = (u32*)smem;
    const int ngroups = (n + SPMM_ROWS - 1) / SPMM_ROWS;
    const int lr = threadIdx.x >> 3;
    const int q  = threadIdx.x & 7;
    for (int g = blockIdx.x; g < ngroups; g += gridDim.x) {
        const int r0 = g * SPMM_ROWS;
        const int rend = min(n, r0 + SPMM_ROWS);
        const int estart = rowptr[r0];
        const int eendb  = rowptr[rend];
        const int ne = eendb - estart;
        const bool lds_ok = (ne <= SPMM_LDSE);
        if (lds_ok) {
            for (int j = threadIdx.x; j < ne; j += 256)
                eld[j] = ecol[estart + j];
        }
        __syncthreads();
        const int r = r0 + lr;
        if (r < n) {
            int e0 = rowptr[r], e1 = rowptr[r + 1];
            float ax0=0,ay0=0, ax1=0,ay1=0, ax2=0,ay2=0, ax3=0,ay3=0;
            if (lds_ok) {
                int le = e0 - estart, le1 = e1 - estart;
                for (; le + 4 <= le1; le += 4) {
                    u32 s0 = eld[le], s1 = eld[le+1], s2 = eld[le+2], s3 = eld[le+3];
                    ushort2 v0 = *((const ushort2*)(in + (size_t)s0 * 16) + q);
                    ushort2 v1 = *((const ushort2*)(in + (size_t)s1 * 16) + q);
                    ushort2 v2 = *((const ushort2*)(in + (size_t)s2 * 16) + q);
                    ushort2 v3 = *((const ushort2*)(in + (size_t)s3 * 16) + q);
                    ax0 += bf2f(v0.x); ay0 += bf2f(v0.y);
                    ax1 += bf2f(v1.x); ay1 += bf2f(v1.y);
                    ax2 += bf2f(v2.x); ay2 += bf2f(v2.y);
                    ax3 += bf2f(v3.x); ay3 += bf2f(v3.y);
                }
                for (; le < le1; ++le) {
                    ushort2 v0 = *((const ushort2*)(in + (size_t)eld[le] * 16) + q);
                    ax0 += bf2f(v0.x); ay0 += bf2f(v0.y);
                }
            } else {
                int e = e0;
                for (; e + 4 <= e1; e += 4) {
                    u32 s0 = ecol[e], s1 = ecol[e+1], s2 = ecol[e+2], s3 = ecol[e+3];
                    ushort2 v0 = *((const ushort2*)(in + (size_t)s0 * 16) + q);
                    ushort2 v1 = *((const ushort2*)(in + (size_t)s1 * 16) + q);
                    ushort2 v2 = *((const ushort2*)(in + (size_t)s2 * 16) + q);
                    ushort2 v3 = *((const ushort2*)(in + (size_t)s3 * 16) + q);
                    ax0 += bf2f(v0.x); ay0 += bf2f(v0.y);
                    ax1 += bf2f(v1.x); ay1 += bf2f(v1.y);
                    ax2 += bf2f(v2.x); ay2 += bf2f(v2.y);
                    ax3 += bf2f(v3.x); ay3 += bf2f(v3.y);
                }
                for (; e < e1; ++e) {
                    ushort2 v0 = *((const ushort2*)(in + (size_t)ecol[e] * 16) + q);
                    ax0 += bf2f(v0.x); ay0 += bf2f(v0.y);
                }
            }
            float Sx = (ax0 + ax1) + (ax2 + ax3);
            float Sy = (ay0 + ay1) + (ay2 + ay3);
            float d1 = dis[r];
            float sc1 = sq1 ? d1 * d1 : d1;
            float Ax = Sx * sc1, Ay = Sy * sc1;
            if (addsrc) {
                ushort2 s = *((const ushort2*)(addsrc + (size_t)r * 16) + q);
                Ax += bf2f(s.x); Ay += bf2f(s.y);
            }
            if (b) {
                Ax += b[2 * q];
                Ay += b[2 * q + 1];
            }
            if (relu) {
                Ax = fmaxf(Ax, 0.f);
                Ay = fmaxf(Ay, 0.f);
            }
            ushort2 o; o.x = f2bf(Ax); o.y = f2bf(Ay);
            *((ushort2*)(out1 + (size_t)r * 16) + q) = o;
            if (out2) {
                ushort2 o2; o2.x = f2bf(Ax * d1); o2.y = f2bf(Ay * d1);
                *((ushort2*)(out2 + (size_t)r * 16) + q) = o2;
            }
        }
        __syncthreads();   // WAR: protect eld before next group restage
    }
}

// ---- phase: GEMM1 (x @ W1 planes, row-normalize, tilde-scale planes 1..3) ----
__device__ void gemm1_phase(char* smem, const float* __restrict__ x,
                            const float* __restrict__ W1,
                            const float* __restrict__ dis,
                            u16* __restrict__ zb, int n, int nstride)
{
    float* As   = (float*)smem;
    float* Bs   = (float*)(smem + 33792);
    float* sums = (float*)(smem + 50176);
    const int t  = threadIdx.x;
    const int tx = t & 15;
    const int ty = t >> 4;
    const int c  = t & 15;
    const int g  = t >> 4;
    const int ntiles = (n + 127) >> 7;
    for (int tile = blockIdx.x; tile < ntiles; tile += gridDim.x) {
        const int block_row = tile << 7;
        float acc[8][4];
        #pragma unroll
        for (int i = 0; i < 8; ++i)
            #pragma unroll
            for (int j = 0; j < 4; ++j) acc[i][j] = 0.f;

        for (int kp = 0; kp < 2; ++kp) {
            #pragma unroll
            for (int i = 0; i < 8; ++i) {
                int row  = g + 16 * i;
                int grow = block_row + row;
                float v0 = 0.f, v1 = 0.f, v2 = 0.f, v3 = 0.f;
                if (grow < n) {
                    const float* xp = x + (long)grow * 128 + kp * 64 + c;
                    v0 = xp[0]; v1 = xp[16]; v2 = xp[32]; v3 = xp[48];
                }
                As[(c +  0) * 132 + row] = v0;
                As[(c + 16) * 132 + row] = v1;
                As[(c + 32) * 132 + row] = v2;
                As[(c + 48) * 132 + row] = v3;
                float red = (v0 + v1) + (v2 + v3);
                #pragma unroll
                for (int off = 8; off > 0; off >>= 1) red += __shfl_down(red, off, 16);
                if (c == 0) { if (kp == 0) sums[row] = red; else sums[row] += red; }
            }
            #pragma unroll
            for (int i2 = 0; i2 < 4; ++i2) {
                int kk = g + 16 * i2;
                int kglob = kp * 64 + kk;
                float4 wv = *(const float4*)(W1 + (c >> 2) * 2048 + kglob * 16 + 4 * (c & 3));
                *(float4*)(Bs + kk * 64 + 4 * c) = wv;
            }
            __syncthreads();
            #pragma unroll 4
            for (int kk = 0; kk < 64; ++kk) {
                float4 a0 = *(const float4*)(As + kk * 132 + 8 * ty);
                float4 a1 = *(const float4*)(As + kk * 132 + 8 * ty + 4);
                float4 bv = *(const float4*)(Bs + kk * 64 + 4 * tx);
                float ar[8] = {a0.x, a0.y, a0.z, a0.w, a1.x, a1.y, a1.z, a1.w};
                float br[4] = {bv.x, bv.y, bv.z, bv.w};
                #pragma unroll
                for (int i = 0; i < 8; ++i)
                    #pragma unroll
                    for (int j = 0; j < 4; ++j)
                        acc[i][j] += ar[i] * br[j];
            }
            __syncthreads();
        }
        int plane = tx >> 2;
        int oo4   = 4 * (tx & 3);
        #pragma unroll
        for (int i = 0; i < 8; ++i) {
            int row  = 8 * ty + i;
            int grow = block_row + row;
            if (grow < n) {
                float s = 1.0f / fmaxf(sums[row], 1e-8f);
                if (plane != 0) s *= dis[grow];          // tilde space for SpMM inputs
                ushort4 o;
                o.x = f2bf(acc[i][0] * s); o.y = f2bf(acc[i][1] * s);
                o.z = f2bf(acc[i][2] * s); o.w = f2bf(acc[i][3] * s);
                *(ushort4*)(zb + (long)plane * nstride + (long)grow * 16 + oo4) = o;
            }
        }
        __syncthreads();
    }
}

// ---- phase: GEMM2 (cat(P0..P3) @ W2cat + b2 -> fp32 out) ----
__device__ void gemm2_phase(char* smem, const u16* __restrict__ zb,
                            const float* __restrict__ W2,
                            const float* __restrict__ b2,
                            float* __restrict__ out, int n, int nstride)
{
    float* As = (float*)smem;
    float* Bs = (float*)(smem + 33792);
    const int t  = threadIdx.x;
    const int tx = t & 15;
    const int ty = t >> 4;
    const int c  = t & 15;
    const int g  = t >> 4;
    const int ntiles = (n + 127) >> 7;
    for (int tile = blockIdx.x; tile < ntiles; tile += gridDim.x) {
        const int block_row = tile << 7;
        float acc[8][4];
        #pragma unroll
        for (int i = 0; i < 8; ++i)
            #pragma unroll
            for (int j = 0; j < 4; ++j) acc[i][j] = 0.f;

        #pragma unroll
        for (int i = 0; i < 8; ++i) {
            int row  = g + 16 * i;
            int grow = block_row + row;
            float v0 = 0.f, v1 = 0.f, v2 = 0.f, v3 = 0.f;
            if (grow < n) {
                const u16* zp = zb + (long)grow * 16 + c;
                v0 = bf2f(zp[0]);
                v1 = bf2f(zp[(long)nstride]);
                v2 = bf2f(zp[2 * (long)nstride]);
                v3 = bf2f(zp[3 * (long)nstride]);
            }
            As[(c +  0) * 132 + row] = v0;
            As[(c + 16) * 132 + row] = v1;
            As[(c + 32) * 132 + row] = v2;
            As[(c + 48) * 132 + row] = v3;
        }
        #pragma unroll
        for (int i2 = 0; i2 < 4; ++i2) {
            int j = g + 16 * i2;
            float4 wv = *(const float4*)(W2 + j * 64 + 4 * c);
            *(float4*)(Bs + j * 64 + 4 * c) = wv;
        }
        __syncthreads();
        #pragma unroll 4
        for (int kk = 0; kk < 64; ++kk) {
            float4 a0 = *(const float4*)(As + kk * 132 + 8 * ty);
            float4 a1 = *(const float4*)(As + kk * 132 + 8 * ty + 4);
            float4 bv = *(const float4*)(Bs + kk * 64 + 4 * tx);
            float ar[8] = {a0.x, a0.y, a0.z, a0.w, a1.x, a1.y, a1.z, a1.w};
            float br[4] = {bv.x, bv.y, bv.z, bv.w};
            #pragma unroll
            for (int i = 0; i < 8; ++i)
                #pragma unroll
                for (int j = 0; j < 4; ++j)
                    acc[i][j] += ar[i] * br[j];
        }
        float4 bias = *(const float4*)(b2 + 4 * tx);
        #pragma unroll
        for (int i = 0; i < 8; ++i) {
            int grow = block_row + 8 * ty + i;
            if (grow < n) {
                float4 o = make_float4(acc[i][0] + bias.x, acc[i][1] + bias.y,
                                       acc[i][2] + bias.z, acc[i][3] + bias.w);
                *(float4*)(out + (long)grow * 64 + 4 * tx) = o;
            }
        }
        __syncthreads();
    }
}

// ==================== the persistent mega-kernel ====================
// 768 blocks x 256 thr; LDS 50688 -> exactly 3 blocks/CU; launch_bounds(256,3)
// caps VGPR at 168 so occupancy can't drop below 3/CU => all blocks co-resident.
__global__ __launch_bounds__(256, 3) void mega_kernel(
    const float* __restrict__ x, const int* __restrict__ srcp,
    const int* __restrict__ dstp,
    const float* __restrict__ W1, const float* __restrict__ b1,
    const float* __restrict__ W2, const float* __restrict__ b2,
    float* __restrict__ out,
    int* bar, int* cnt, int* rowptr, int* cursor, float* dis,
    u16* zb, u32* ecol, int n, int E, int nstride)
{
    __shared__ __align__(16) char smem[MEGA_LDS];
    const int gstride = (int)gridDim.x * 256;

    // P1: in-degree count (cnt zeroed by preceding memset)
    for (int e = blockIdx.x * 256 + threadIdx.x; e < E; e += gstride)
        atomicAdd(&cnt[dstp[e]], 1);
    grid_bar(bar, 1);

    // P2: scan -> rowptr / cursor / dis (block 0 only)
    scan_phase(smem, cnt, rowptr, cursor, dis, n);
    grid_bar(bar, 2);

    // P3: scatter edges into CSR (atomic cursors) THEN gemm1 — independent
    // (scatter touches ecol/cursor; gemm1 touches x/W1/dis only), so no
    // grid barrier between them.
    for (int e = blockIdx.x * 256 + threadIdx.x; e < E; e += gstride) {
        int d = dstp[e];
        int p = atomicAdd(&cursor[d], 1);
        ecol[p] = (u32)srcp[e];
    }
    gemm1_phase(smem, x, W1, dis, zb, n, nstride);
    grid_bar(bar, 3);

    u16 *P0 = zb, *P1 = zb + nstride, *P2 = zb + 2 * nstride, *P3 = zb + 3 * nstride;
    u16 *T0 = zb + 4 * nstride, *T1 = zb + 5 * nstride;

    // L1 Horner (tilde space: scale1 = dis^2)
    spmm_phase(smem, P3, P2, P2, nullptr, rowptr, ecol, dis, nullptr, 0, 1, n);
    grid_bar(bar, 4);
    spmm_phase(smem, P2, P1, P1, nullptr, rowptr, ecol, dis, nullptr, 0, 1, n);
    grid_bar(bar, 5);
    // h1 = relu(z0 + dis*S + b1); T0 = dis*h1
    spmm_phase(smem, P1, P0, P0, T0, rowptr, ecol, dis, b1, 1, 0, n);
    grid_bar(bar, 6);
    // L2 hops: g_k = dis*S (gemm2 input), tilde copy = dis*g_k
    spmm_phase(smem, T0, nullptr, P1, T1, rowptr, ecol, dis, nullptr, 0, 0, n);
    grid_bar(bar, 7);
    spmm_phase(smem, T1, nullptr, P2, T0, rowptr, ecol, dis, nullptr, 0, 0, n);
    grid_bar(bar, 8);
    spmm_phase(smem, T0, nullptr, P3, nullptr, rowptr, ecol, dis, nullptr, 0, 0, n);
    grid_bar(bar, 9);

    // P11: GEMM2 -> out
    gemm2_phase(smem, zb, W2, b2, out, n, nstride);
}

// ================= fp32 fallback path (small workspace) =================
__global__ void deg_kernel(const int* __restrict__ dst, float* __restrict__ deg, int E) {
    int e = blockIdx.x * blockDim.x + threadIdx.x;
    if (e < E) atomicAdd(&deg[dst[e]], 1.0f);
}
__global__ void disf_kernel(float* __restrict__ deg, int n) {
    int i = blockIdx.x * blockDim.x + threadIdx.x;
    if (i < n) {
        float d = deg[i];
        deg[i] = (d > 0.0f) ? rsqrtf(d) : 0.0f;
    }
}
__global__ __launch_bounds__(256) void gemm1_f32_kernel(
    const float* __restrict__ x, const float* __restrict__ W1,
    float* __restrict__ z, int n, int nstride)
{
    __shared__ float As[64 * 132];
    __shared__ float Bs[64 * 64];
    __shared__ float sums[128];
    const int t  = threadIdx.x;
    const int tx = t & 15;
    const int ty = t >> 4;
    const int c  = t & 15;
    const int g  = t >> 4;
    const int block_row = blockIdx.x * 128;
    float acc[8][4];
    #pragma unroll
    for (int i = 0; i < 8; ++i)
        #pragma unroll
        for (int j = 0; j < 4; ++j) acc[i][j] = 0.f;
    for (int kp = 0; kp < 2; ++kp) {
        #pragma unroll
        for (int i = 0; i < 8; ++i) {
            int row  = g + 16 * i;
            int grow = block_row + row;
            float v0 = 0.f, v1 = 0.f, v2 = 0.f, v3 = 0.f;
            if (grow < n) {
                const float* xp = x + (long)grow * 128 + kp * 64 + c;
                v0 = xp[0]; v1 = xp[16]; v2 = xp[32]; v3 = xp[48];
            }
            As[(c +  0) * 132 + row] = v0;
            As[(c + 16) * 132 + row] = v1;
            As[(c + 32) * 132 + row] = v2;
            As[(c + 48) * 132 + row] = v3;
            float red = (v0 + v1) + (v2 + v3);
            #pragma unroll
            for (int off = 8; off > 0; off >>= 1) red += __shfl_down(red, off, 16);
            if (c == 0) { if (kp == 0) sums[row] = red; else sums[row] += red; }
        }
        #pragma unroll
        for (int i2 = 0; i2 < 4; ++i2) {
            int kk = g + 16 * i2;
            int kglob = kp * 64 + kk;
            float4 wv = *(const float4*)(W1 + (c >> 2) * 2048 + kglob * 16 + 4 * (c & 3));
            *(float4*)(Bs + kk * 64 + 4 * c) = wv;
        }
        __syncthreads();
        #pragma unroll 4
        for (int kk = 0; kk < 64; ++kk) {
            float4 a0 = *(const float4*)(As + kk * 132 + 8 * ty);
            float4 a1 = *(const float4*)(As + kk * 132 + 8 * ty + 4);
            float4 bv = *(const float4*)(Bs + kk * 64 + 4 * tx);
            float ar[8] = {a0.x, a0.y, a0.z, a0.w, a1.x, a1.y, a1.z, a1.w};
            float br[4] = {bv.x, bv.y, bv.z, bv.w};
            #pragma unroll
            for (int i = 0; i < 8; ++i)
                #pragma unroll
                for (int j = 0; j < 4; ++j)
                    acc[i][j] += ar[i] * br[j];
        }
        __syncthreads();
    }
    int plane = tx >> 2;
    int oo4   = 4 * (tx & 3);
    #pragma unroll
    for (int i = 0; i < 8; ++i) {
        int row  = 8 * ty + i;
        int grow = block_row + row;
        if (grow < n) {
            float s = 1.0f / fmaxf(sums[row], 1e-8f);
            float4 o = make_float4(acc[i][0] * s, acc[i][1] * s, acc[i][2] * s, acc[i][3] * s);
            *(float4*)(z + (long)plane * nstride + (long)grow * 16 + oo4) = o;
        }
    }
}
__global__ __launch_bounds__(256) void spmm_atomic_kernel(
    const float* __restrict__ in, float* __restrict__ out,
    const int* __restrict__ src, const int* __restrict__ dst,
    const float* __restrict__ dis, int E)
{
    int t = blockIdx.x * blockDim.x + threadIdx.x;
    int e = t >> 4, f = t & 15;
    if (e < E) {
        int s = src[e], d = dst[e];
        atomicAdd(&out[d * 16 + f], dis[s] * dis[d] * in[s * 16 + f]);
    }
}
__global__ void bias_relu_kernel(float* __restrict__ z0, const float* __restrict__ b, int total) {
    int i = blockIdx.x * blockDim.x + threadIdx.x;
    if (i < total) {
        float v = z0[i] + b[i & 15];
        z0[i] = v > 0.0f ? v : 0.0f;
    }
}
__global__ __launch_bounds__(256) void gemm2_f32_kernel(
    const float* __restrict__ z, const float* __restrict__ W2,
    const float* __restrict__ b2, float* __restrict__ out, int n, int nstride)
{
    __shared__ float As[64 * 132];
    __shared__ float Bs[64 * 64];
    const int t  = threadIdx.x;
    const int tx = t & 15;
    const int ty = t >> 4;
    const int c  = t & 15;
    const int g  = t >> 4;
    const int block_row = blockIdx.x * 128;
    float acc[8][4];
    #pragma unroll
    for (int i = 0; i < 8; ++i)
        #pragma unroll
        for (int j = 0; j < 4; ++j) acc[i][j] = 0.f;
    #pragma unroll
    for (int i = 0; i < 8; ++i) {
        int row  = g + 16 * i;
        int grow = block_row + row;
        float v0 = 0.f, v1 = 0.f, v2 = 0.f, v3 = 0.f;
        if (grow < n) {
            const float* zp = z + (long)grow * 16 + c;
            v0 = zp[0];
            v1 = zp[(long)nstride];
            v2 = zp[2 * (long)nstride];
            v3 = zp[3 * (long)nstride];
        }
        As[(c +  0) * 132 + row] = v0;
        As[(c + 16) * 132 + row] = v1;
        As[(c + 32) * 132 + row] = v2;
        As[(c + 48) * 132 + row] = v3;
    }
    #pragma unroll
    for (int i2 = 0; i2 < 4; ++i2) {
        int j = g + 16 * i2;
        float4 wv = *(const float4*)(W2 + j * 64 + 4 * c);
        *(float4*)(Bs + j * 64 + 4 * c) = wv;
    }
    __syncthreads();
    #pragma unroll 4
    for (int kk = 0; kk < 64; ++kk) {
        float4 a0 = *(const float4*)(As + kk * 132 + 8 * ty);
        float4 a1 = *(const float4*)(As + kk * 132 + 8 * ty + 4);
        float4 bv = *(const float4*)(Bs + kk * 64 + 4 * tx);
        float ar[8] = {a0.x, a0.y, a0.z, a0.w, a1.x, a1.y, a1.z, a1.w};
        float br[4] = {bv.x, bv.y, bv.z, bv.w};
        #pragma unroll
        for (int i = 0; i < 8; ++i)
            #pragma unroll
            for (int j = 0; j < 4; ++j)
                acc[i][j] += ar[i] * br[j];
    }
    float4 bias = *(const float4*)(b2 + 4 * tx);
    #pragma unroll
    for (int i = 0; i < 8; ++i) {
        int grow = block_row + 8 * ty + i;
        if (grow < n) {
            float4 o = make_float4(acc[i][0] + bias.x, acc[i][1] + bias.y,
                                   acc[i][2] + bias.z, acc[i][3] + bias.w);
            *(float4*)(out + (long)grow * 64 + 4 * tx) = o;
        }
    }
}

static inline size_t align16(size_t v) { return (v + 15) & ~(size_t)15; }

extern "C" void kernel_launch(void* const* d_in, const int* in_sizes, int n_in,
                              void* d_out, int out_size, void* d_ws, size_t ws_size,
                              hipStream_t stream) {
    const float* x   = (const float*)d_in[0];
    const int*   ei  = (const int*)d_in[1];
    const float* W1  = (const float*)d_in[2];
    const float* b1  = (const float*)d_in[3];
    const float* W2  = (const float*)d_in[4];
    const float* bb2 = (const float*)d_in[5];
    float* out = (float*)d_out;

    const int n  = in_sizes[0] / 128;   // 50000
    const int E  = in_sizes[1] / 2;     // 800000
    const int NS = n * 16;

    const int* srcp = ei;
    const int* dstp = ei + E;

    char* wsb = (char*)d_ws;
    // layout: bar(16B) | cnt[n] | rowptr[n+1] | cursor[n] | dis[n] | zb[6*NS u16] | ecol[E u32]
    int*   bar    = (int*)wsb;
    int*   cnt    = (int*)(wsb + 16);
    int*   rowptr = (int*)(wsb + 16 + (size_t)4 * n);
    int*   cursor = (int*)(wsb + 16 + (size_t)4 * (2 * n + 1));
    float* dis    = (float*)(wsb + 16 + (size_t)4 * (3 * n + 1));
    size_t zoffb  = align16(16 + (size_t)4 * (4 * n + 1));
    u16*   zb     = (u16*)(wsb + zoffb);
    size_t ecooff = align16(zoffb + (size_t)2 * 6 * NS);
    u32*   ecol   = (u32*)(wsb + ecooff);
    size_t need   = ecooff + (size_t)4 * E;

    if (ws_size >= need) {
        // zero bar counter + degree counts, then one persistent kernel for everything
        hipMemsetAsync(wsb, 0, 16 + (size_t)4 * n, stream);
        mega_kernel<<<MEGA_GRID, 256, 0, stream>>>(
            x, srcp, dstp, W1, b1, W2, bb2, out,
            bar, cnt, rowptr, cursor, dis, zb, ecol, n, E, NS);
    } else {
        // ---------- fp32 atomic fallback ----------
        int gemm_blocks = (n + 127) / 128;
        float* ws = (float*)d_ws;
        float* dis2 = ws;
        size_t z2off = ((size_t)n + 3) & ~(size_t)3;
        float* z2 = ws + z2off;
        hipMemsetAsync(dis2, 0, n * sizeof(float), stream);
        deg_kernel<<<(E + 255) / 256, 256, 0, stream>>>(dstp, dis2, E);
        disf_kernel<<<(n + 255) / 256, 256, 0, stream>>>(dis2, n);
        gemm1_f32_kernel<<<gemm_blocks, 256, 0, stream>>>(x, W1, z2, n, NS);
        int sb = (16 * E + 255) / 256;
        spmm_atomic_kernel<<<sb, 256, 0, stream>>>(z2 + 3 * NS, z2 + 2 * NS, srcp, dstp, dis2, E);
        spmm_atomic_kernel<<<sb, 256, 0, stream>>>(z2 + 2 * NS, z2 + 1 * NS, srcp, dstp, dis2, E);
        spmm_atomic_kernel<<<sb, 256, 0, stream>>>(z2 + 1 * NS, z2,          srcp, dstp, dis2, E);
        bias_relu_kernel<<<(NS + 255) / 256, 256, 0, stream>>>(z2, b1, NS);
        hipMemsetAsync(z2 + NS, 0, (size_t)3 * NS * sizeof(float), stream);
        spmm_atomic_kernel<<<sb, 256, 0, stream>>>(z2,          z2 + NS,     srcp, dstp, dis2, E);
        spmm_atomic_kernel<<<sb, 256, 0, stream>>>(z2 + NS,     z2 + 2 * NS, srcp, dstp, dis2, E);
        spmm_atomic_kernel<<<sb, 256, 0, stream>>>(z2 + 2 * NS, z2 + 3 * NS, srcp, dstp, dis2, E);
        gemm2_f32_kernel<<<gemm_blocks, 256, 0, stream>>>(z2, W2, bb2, out, n, NS);
    }
}

// Round 3
// 618.786 us; speedup vs baseline: 6.2921x; 1.5963x over previous
//
#include <hip/hip_runtime.h>
#include <hip/hip_bf16.h>

typedef unsigned short u16;
typedef unsigned int u32;

__device__ __forceinline__ float bf2f(u16 h) {
    return __uint_as_float(((u32)h) << 16);
}
__device__ __forceinline__ u16 f2bf(float f) {
    __hip_bfloat16 h = __float2bfloat16(f);   // RNE
    return *reinterpret_cast<u16*>(&h);
}

#define MEGA_GRID 768          // 256 CU x 3 blocks/CU (LDS-limited, see launch_bounds)
#define SPMM_ROWS 32
#define SPMM_LDSE 2048
// smem layout: As[64*132]f @0 (33792B) | Bs[64*64]f @33792 (16384B) | sums[128]f @50176 (512B)
#define MEGA_LDS  50688

// ---------- agent-scope relaxed accessors ----------
// ALL cross-phase intermediates (cnt/rowptr/cursor/dis/partial/zb/ecol) are
// accessed ONLY through these. They compile to cache-bypassing loads/stores
// coherent at the Infinity-Cache point, so no L1/L2 line of any intermediate
// ever exists -> grid barriers need NO wbl2/inv fences at all.
__device__ __forceinline__ u32 ldw(const u32* p) {
    return __hip_atomic_load((u32*)p, __ATOMIC_RELAXED, __HIP_MEMORY_SCOPE_AGENT);
}
__device__ __forceinline__ void stw(u32* p, u32 v) {
    __hip_atomic_store(p, v, __ATOMIC_RELAXED, __HIP_MEMORY_SCOPE_AGENT);
}
__device__ __forceinline__ int ldi(const int* p) {
    return __hip_atomic_load((int*)p, __ATOMIC_RELAXED, __HIP_MEMORY_SCOPE_AGENT);
}
__device__ __forceinline__ void sti(int* p, int v) {
    __hip_atomic_store(p, v, __ATOMIC_RELAXED, __HIP_MEMORY_SCOPE_AGENT);
}
__device__ __forceinline__ float ldf(const float* p) {
    return __hip_atomic_load((float*)p, __ATOMIC_RELAXED, __HIP_MEMORY_SCOPE_AGENT);
}
__device__ __forceinline__ void stf(float* p, float v) {
    __hip_atomic_store(p, v, __ATOMIC_RELAXED, __HIP_MEMORY_SCOPE_AGENT);
}
__device__ __forceinline__ float lo16f(u32 w) { return __uint_as_float(w << 16); }
__device__ __forceinline__ float hi16f(u32 w) { return __uint_as_float(w & 0xffff0000u); }
__device__ __forceinline__ u32 packbf(float a, float b) {
    return (u32)f2bf(a) | ((u32)f2bf(b) << 16);
}

// ---- device-wide barrier: pure relaxed counter, ZERO cache maintenance ----
__device__ __forceinline__ void grid_bar(int* bar, int epoch) {
    __syncthreads();    // drains this block's vmem (vmcnt 0) before arrival
    if (threadIdx.x == 0) {
        __hip_atomic_fetch_add(bar, 1, __ATOMIC_RELAXED, __HIP_MEMORY_SCOPE_AGENT);
        const int tgt = epoch * MEGA_GRID;
        while (__hip_atomic_load(bar, __ATOMIC_RELAXED, __HIP_MEMORY_SCOPE_AGENT) < tgt)
            __builtin_amdgcn_s_sleep(4);
    }
    __syncthreads();
}

// ---- distributed scan, 3 sub-phases (each ~1-2us at MALL latency) ----
// P2a: block b sums its chunk of cnt -> partial[b]
__device__ void scan_partial(char* smem, const int* cnt, int* partial, int n) {
    int* sc = (int*)smem;
    const int per = (n + MEGA_GRID - 1) / MEGA_GRID;   // <=256 guarded by host
    const int s = (int)blockIdx.x * per;
    const int t = threadIdx.x;
    int i = s + t;
    int v = (t < per && i < n) ? ldi(cnt + i) : 0;
    sc[t] = v;
    __syncthreads();
    #pragma unroll
    for (int off = 128; off > 0; off >>= 1) {
        if (t < off) sc[t] += sc[t + off];
        __syncthreads();
    }
    if (t == 0) sti(partial + blockIdx.x, sc[0]);
}

// P2b: block 0 exclusive-scans partial[0..MEGA_GRID)
__device__ void scan_bases(char* smem, int* partial) {
    if (blockIdx.x != 0) return;
    int* sc = (int*)smem;
    const int t = threadIdx.x;
    const int K = (MEGA_GRID + 255) / 256;   // 3
    int p[K];
    int lsum = 0;
    #pragma unroll
    for (int j = 0; j < K; ++j) {
        int idx = t * K + j;
        p[j] = (idx < MEGA_GRID) ? ldi(partial + idx) : 0;
        lsum += p[j];
    }
    sc[t] = lsum;
    __syncthreads();
    #pragma unroll
    for (int off = 1; off < 256; off <<= 1) {
        int u = (t >= off) ? sc[t - off] : 0;
        __syncthreads();
        sc[t] += u;
        __syncthreads();
    }
    int run = sc[t] - lsum;   // exclusive prefix of this thread's group
    #pragma unroll
    for (int j = 0; j < K; ++j) {
        int idx = t * K + j;
        if (idx < MEGA_GRID) sti(partial + idx, run);
        run += p[j];
    }
}

// P2c: block b scans its chunk -> rowptr/cursor/dis
__device__ void scan_final(char* smem, const int* cnt, const int* partial,
                           int* rowptr, int* cursor, float* dis, int n, int E) {
    int* sc = (int*)smem;
    const int per = (n + MEGA_GRID - 1) / MEGA_GRID;
    const int s = (int)blockIdx.x * per;
    const int t = threadIdx.x;
    int i = s + t;
    bool act = (t < per && i < n);
    int v = act ? ldi(cnt + i) : 0;
    sc[t] = v;
    __syncthreads();
    #pragma unroll
    for (int off = 1; off < 256; off <<= 1) {
        int u = (t >= off) ? sc[t - off] : 0;
        __syncthreads();
        sc[t] += u;
        __syncthreads();
    }
    int excl = sc[t] - v;
    if (act) {
        int rp = ldi(partial + blockIdx.x) + excl;
        sti(rowptr + i, rp);
        sti(cursor + i, rp);
        stf(dis + i, (v > 0) ? rsqrtf((float)v) : 0.0f);
    }
    if (blockIdx.x == 0 && t == 0) sti(rowptr + n, E);
}

// ---- phase: CSR SpMM (tilde form), grid-strided over 32-row groups ----
__device__ void spmm_phase(char* smem,
    const u16* __restrict__ in, const u16* __restrict__ addsrc,
    u16* __restrict__ out1, u16* __restrict__ out2,
    const int* __restrict__ rowptr, const u32* __restrict__ ecol,
    const float* __restrict__ dis, const float* __restrict__ b,
    int relu, int sq1, int n)
{
    u32* eld = (u32*)smem;
    const u32* inw = (const u32*)in;
    const int ngroups = (n + SPMM_ROWS - 1) / SPMM_ROWS;
    const int lr = threadIdx.x >> 3;
    const int q  = threadIdx.x & 7;
    for (int g = blockIdx.x; g < ngroups; g += MEGA_GRID) {
        const int r0 = g * SPMM_ROWS;
        const int rend = min(n, r0 + SPMM_ROWS);
        const int estart = ldi(rowptr + r0);
        const int eendb  = ldi(rowptr + rend);
        const int ne = eendb - estart;
        const bool lds_ok = (ne <= SPMM_LDSE);
        if (lds_ok) {
            for (int j = threadIdx.x; j < ne; j += 256)
                eld[j] = ldw(ecol + estart + j);
        }
        __syncthreads();
        const int r = r0 + lr;
        if (r < n) {
            int e0 = ldi(rowptr + r), e1 = ldi(rowptr + r + 1);
            float ax0=0,ay0=0, ax1=0,ay1=0, ax2=0,ay2=0, ax3=0,ay3=0;
            if (lds_ok) {
                int le = e0 - estart, le1 = e1 - estart;
                for (; le + 4 <= le1; le += 4) {
                    u32 s0 = eld[le], s1 = eld[le+1], s2 = eld[le+2], s3 = eld[le+3];
                    u32 w0 = ldw(inw + (size_t)s0 * 8 + q);
                    u32 w1 = ldw(inw + (size_t)s1 * 8 + q);
                    u32 w2 = ldw(inw + (size_t)s2 * 8 + q);
                    u32 w3 = ldw(inw + (size_t)s3 * 8 + q);
                    ax0 += lo16f(w0); ay0 += hi16f(w0);
                    ax1 += lo16f(w1); ay1 += hi16f(w1);
                    ax2 += lo16f(w2); ay2 += hi16f(w2);
                    ax3 += lo16f(w3); ay3 += hi16f(w3);
                }
                for (; le < le1; ++le) {
                    u32 w0 = ldw(inw + (size_t)eld[le] * 8 + q);
                    ax0 += lo16f(w0); ay0 += hi16f(w0);
                }
            } else {
                int e = e0;
                for (; e + 4 <= e1; e += 4) {
                    u32 s0 = ldw(ecol+e), s1 = ldw(ecol+e+1), s2 = ldw(ecol+e+2), s3 = ldw(ecol+e+3);
                    u32 w0 = ldw(inw + (size_t)s0 * 8 + q);
                    u32 w1 = ldw(inw + (size_t)s1 * 8 + q);
                    u32 w2 = ldw(inw + (size_t)s2 * 8 + q);
                    u32 w3 = ldw(inw + (size_t)s3 * 8 + q);
                    ax0 += lo16f(w0); ay0 += hi16f(w0);
                    ax1 += lo16f(w1); ay1 += hi16f(w1);
                    ax2 += lo16f(w2); ay2 += hi16f(w2);
                    ax3 += lo16f(w3); ay3 += hi16f(w3);
                }
                for (; e < e1; ++e) {
                    u32 w0 = ldw(inw + (size_t)ldw(ecol + e) * 8 + q);
                    ax0 += lo16f(w0); ay0 += hi16f(w0);
                }
            }
            float Sx = (ax0 + ax1) + (ax2 + ax3);
            float Sy = (ay0 + ay1) + (ay2 + ay3);
            float d1 = ldf(dis + r);
            float sc1 = sq1 ? d1 * d1 : d1;
            float Ax = Sx * sc1, Ay = Sy * sc1;
            if (addsrc) {
                u32 s = ldw((const u32*)addsrc + (size_t)r * 8 + q);
                Ax += lo16f(s); Ay += hi16f(s);
            }
            if (b) {           // kernel input, normally cached
                Ax += b[2 * q];
                Ay += b[2 * q + 1];
            }
            if (relu) {
                Ax = fmaxf(Ax, 0.f);
                Ay = fmaxf(Ay, 0.f);
            }
            stw((u32*)out1 + (size_t)r * 8 + q, packbf(Ax, Ay));
            if (out2)
                stw((u32*)out2 + (size_t)r * 8 + q, packbf(Ax * d1, Ay * d1));
        }
        __syncthreads();   // WAR: protect eld before next group restage
    }
}

// ---- phase: GEMM1 (x @ W1 planes, row-normalize, tilde-scale planes 1..3) ----
__device__ void gemm1_phase(char* smem, const float* __restrict__ x,
                            const float* __restrict__ W1,
                            const float* __restrict__ dis,
                            u16* __restrict__ zb, int n, int nstride)
{
    float* As   = (float*)smem;
    float* Bs   = (float*)(smem + 33792);
    float* sums = (float*)(smem + 50176);
    const int t  = threadIdx.x;
    const int tx = t & 15;
    const int ty = t >> 4;
    const int c  = t & 15;
    const int g  = t >> 4;
    const int ntiles = (n + 127) >> 7;
    for (int tile = blockIdx.x; tile < ntiles; tile += MEGA_GRID) {
        const int block_row = tile << 7;
        float acc[8][4];
        #pragma unroll
        for (int i = 0; i < 8; ++i)
            #pragma unroll
            for (int j = 0; j < 4; ++j) acc[i][j] = 0.f;

        for (int kp = 0; kp < 2; ++kp) {
            #pragma unroll
            for (int i = 0; i < 8; ++i) {
                int row  = g + 16 * i;
                int grow = block_row + row;
                float v0 = 0.f, v1 = 0.f, v2 = 0.f, v3 = 0.f;
                if (grow < n) {
                    const float* xp = x + (long)grow * 128 + kp * 64 + c;
                    v0 = xp[0]; v1 = xp[16]; v2 = xp[32]; v3 = xp[48];
                }
                As[(c +  0) * 132 + row] = v0;
                As[(c + 16) * 132 + row] = v1;
                As[(c + 32) * 132 + row] = v2;
                As[(c + 48) * 132 + row] = v3;
                float red = (v0 + v1) + (v2 + v3);
                #pragma unroll
                for (int off = 8; off > 0; off >>= 1) red += __shfl_down(red, off, 16);
                if (c == 0) { if (kp == 0) sums[row] = red; else sums[row] += red; }
            }
            #pragma unroll
            for (int i2 = 0; i2 < 4; ++i2) {
                int kk = g + 16 * i2;
                int kglob = kp * 64 + kk;
                float4 wv = *(const float4*)(W1 + (c >> 2) * 2048 + kglob * 16 + 4 * (c & 3));
                *(float4*)(Bs + kk * 64 + 4 * c) = wv;
            }
            __syncthreads();
            #pragma unroll 4
            for (int kk = 0; kk < 64; ++kk) {
                float4 a0 = *(const float4*)(As + kk * 132 + 8 * ty);
                float4 a1 = *(const float4*)(As + kk * 132 + 8 * ty + 4);
                float4 bv = *(const float4*)(Bs + kk * 64 + 4 * tx);
                float ar[8] = {a0.x, a0.y, a0.z, a0.w, a1.x, a1.y, a1.z, a1.w};
                float br[4] = {bv.x, bv.y, bv.z, bv.w};
                #pragma unroll
                for (int i = 0; i < 8; ++i)
                    #pragma unroll
                    for (int j = 0; j < 4; ++j)
                        acc[i][j] += ar[i] * br[j];
            }
            __syncthreads();
        }
        int plane = tx >> 2;
        int oo4   = 4 * (tx & 3);
        #pragma unroll
        for (int i = 0; i < 8; ++i) {
            int row  = 8 * ty + i;
            int grow = block_row + row;
            if (grow < n) {
                float s = 1.0f / fmaxf(sums[row], 1e-8f);
                if (plane != 0) s *= ldf(dis + grow);    // tilde space for SpMM inputs
                u32* zp = (u32*)zb + (size_t)plane * (nstride >> 1) + (size_t)grow * 8 + (oo4 >> 1);
                stw(zp,     packbf(acc[i][0] * s, acc[i][1] * s));
                stw(zp + 1, packbf(acc[i][2] * s, acc[i][3] * s));
            }
        }
        __syncthreads();
    }
}

// ---- phase: GEMM2 (cat(P0..P3) @ W2cat + b2 -> fp32 out) ----
__device__ void gemm2_phase(char* smem, const u16* __restrict__ zb,
                            const float* __restrict__ W2,
                            const float* __restrict__ b2,
                            float* __restrict__ out, int n, int nstride)
{
    float* As = (float*)smem;
    float* Bs = (float*)(smem + 33792);
    const u32* zw = (const u32*)zb;
    const int nsw = nstride >> 1;     // u32 stride per plane
    const int t  = threadIdx.x;
    const int tx = t & 15;
    const int ty = t >> 4;
    const int c  = t & 15;
    const int g  = t >> 4;
    const int ntiles = (n + 127) >> 7;
    for (int tile = blockIdx.x; tile < ntiles; tile += MEGA_GRID) {
        const int block_row = tile << 7;
        float acc[8][4];
        #pragma unroll
        for (int i = 0; i < 8; ++i)
            #pragma unroll
            for (int j = 0; j < 4; ++j) acc[i][j] = 0.f;

        // staging: threads c=0..7 load pair c of planes 0,1; c=8..15 pair c-8 of planes 2,3
        #pragma unroll
        for (int i = 0; i < 8; ++i) {
            int row  = g + 16 * i;
            int grow = block_row + row;
            int pr   = c & 7;                       // pair index 0..7
            int pl   = (c < 8) ? 0 : 2;             // first plane this thread stages
            float l0 = 0.f, h0 = 0.f, l1 = 0.f, h1 = 0.f;
            if (grow < n) {
                u32 w0 = ldw(zw + (size_t)pl * nsw       + (size_t)grow * 8 + pr);
                u32 w1 = ldw(zw + (size_t)(pl + 1) * nsw + (size_t)grow * 8 + pr);
                l0 = lo16f(w0); h0 = hi16f(w0);
                l1 = lo16f(w1); h1 = hi16f(w1);
            }
            int col = pl * 16 + 2 * pr;
            As[(col +  0) * 132 + row] = l0;
            As[(col +  1) * 132 + row] = h0;
            As[(col + 16) * 132 + row] = l1;
            As[(col + 17) * 132 + row] = h1;
        }
        #pragma unroll
        for (int i2 = 0; i2 < 4; ++i2) {
            int j = g + 16 * i2;
            float4 wv = *(const float4*)(W2 + j * 64 + 4 * c);
            *(float4*)(Bs + j * 64 + 4 * c) = wv;
        }
        __syncthreads();
        #pragma unroll 4
        for (int kk = 0; kk < 64; ++kk) {
            float4 a0 = *(const float4*)(As + kk * 132 + 8 * ty);
            float4 a1 = *(const float4*)(As + kk * 132 + 8 * ty + 4);
            float4 bv = *(const float4*)(Bs + kk * 64 + 4 * tx);
            float ar[8] = {a0.x, a0.y, a0.z, a0.w, a1.x, a1.y, a1.z, a1.w};
            float br[4] = {bv.x, bv.y, bv.z, bv.w};
            #pragma unroll
            for (int i = 0; i < 8; ++i)
                #pragma unroll
                for (int j = 0; j < 4; ++j)
                    acc[i][j] += ar[i] * br[j];
        }
        float4 bias = *(const float4*)(b2 + 4 * tx);
        #pragma unroll
        for (int i = 0; i < 8; ++i) {
            int grow = block_row + 8 * ty + i;
            if (grow < n) {
                float4 o = make_float4(acc[i][0] + bias.x, acc[i][1] + bias.y,
                                       acc[i][2] + bias.z, acc[i][3] + bias.w);
                *(float4*)(out + (long)grow * 64 + 4 * tx) = o;   // flushed at kernel end
            }
        }
        __syncthreads();
    }
}

// ==================== the persistent mega-kernel ====================
__global__ __launch_bounds__(256, 3) void mega_kernel(
    const float* __restrict__ x, const int* __restrict__ srcp,
    const int* __restrict__ dstp,
    const float* __restrict__ W1, const float* __restrict__ b1,
    const float* __restrict__ W2, const float* __restrict__ b2,
    float* __restrict__ out,
    int* bar, int* cnt, int* rowptr, int* cursor, float* dis, int* partial,
    u16* zb, u32* ecol, int n, int E, int nstride)
{
    __shared__ __align__(16) char smem[MEGA_LDS];
    const int gstride = MEGA_GRID * 256;

    // P1: in-degree count (cnt zeroed by preceding memset; agent-scope RMW)
    for (int e = blockIdx.x * 256 + threadIdx.x; e < E; e += gstride)
        __hip_atomic_fetch_add(cnt + dstp[e], 1, __ATOMIC_RELAXED, __HIP_MEMORY_SCOPE_AGENT);
    grid_bar(bar, 1);

    // P2: distributed scan
    scan_partial(smem, cnt, partial, n);
    grid_bar(bar, 2);
    scan_bases(smem, partial);
    grid_bar(bar, 3);
    scan_final(smem, cnt, partial, rowptr, cursor, dis, n, E);
    grid_bar(bar, 4);

    // P3: scatter edges into CSR (atomic cursors) THEN gemm1 — independent
    for (int e = blockIdx.x * 256 + threadIdx.x; e < E; e += gstride) {
        int d = dstp[e];
        int p = __hip_atomic_fetch_add(cursor + d, 1, __ATOMIC_RELAXED, __HIP_MEMORY_SCOPE_AGENT);
        stw(ecol + p, (u32)srcp[e]);
    }
    gemm1_phase(smem, x, W1, dis, zb, n, nstride);
    grid_bar(bar, 5);

    u16 *P0 = zb, *P1 = zb + nstride, *P2 = zb + 2 * nstride, *P3 = zb + 3 * nstride;
    u16 *T0 = zb + 4 * nstride, *T1 = zb + 5 * nstride;

    // L1 Horner (tilde space: scale1 = dis^2)
    spmm_phase(smem, P3, P2, P2, nullptr, rowptr, ecol, dis, nullptr, 0, 1, n);
    grid_bar(bar, 6);
    spmm_phase(smem, P2, P1, P1, nullptr, rowptr, ecol, dis, nullptr, 0, 1, n);
    grid_bar(bar, 7);
    // h1 = relu(z0 + dis*S + b1); T0 = dis*h1
    spmm_phase(smem, P1, P0, P0, T0, rowptr, ecol, dis, b1, 1, 0, n);
    grid_bar(bar, 8);
    // L2 hops: g_k = dis*S (gemm2 input), tilde copy = dis*g_k
    spmm_phase(smem, T0, nullptr, P1, T1, rowptr, ecol, dis, nullptr, 0, 0, n);
    grid_bar(bar, 9);
    spmm_phase(smem, T1, nullptr, P2, T0, rowptr, ecol, dis, nullptr, 0, 0, n);
    grid_bar(bar, 10);
    spmm_phase(smem, T0, nullptr, P3, nullptr, rowptr, ecol, dis, nullptr, 0, 0, n);
    grid_bar(bar, 11);

    // P11: GEMM2 -> out
    gemm2_phase(smem, zb, W2, b2, out, n, nstride);
}

// ================= fp32 fallback path (small workspace) =================
__global__ void deg_kernel(const int* __restrict__ dst, float* __restrict__ deg, int E) {
    int e = blockIdx.x * blockDim.x + threadIdx.x;
    if (e < E) atomicAdd(&deg[dst[e]], 1.0f);
}
__global__ void disf_kernel(float* __restrict__ deg, int n) {
    int i = blockIdx.x * blockDim.x + threadIdx.x;
    if (i < n) {
        float d = deg[i];
        deg[i] = (d > 0.0f) ? rsqrtf(d) : 0.0f;
    }
}
__global__ __launch_bounds__(256) void gemm1_f32_kernel(
    const float* __restrict__ x, const float* __restrict__ W1,
    float* __restrict__ z, int n, int nstride)
{
    __shared__ float As[64 * 132];
    __shared__ float Bs[64 * 64];
    __shared__ float sums[128];
    const int t  = threadIdx.x;
    const int tx = t & 15;
    const int ty = t >> 4;
    const int c  = t & 15;
    const int g  = t >> 4;
    const int block_row = blockIdx.x * 128;
    float acc[8][4];
    #pragma unroll
    for (int i = 0; i < 8; ++i)
        #pragma unroll
        for (int j = 0; j < 4; ++j) acc[i][j] = 0.f;
    for (int kp = 0; kp < 2; ++kp) {
        #pragma unroll
        for (int i = 0; i < 8; ++i) {
            int row  = g + 16 * i;
            int grow = block_row + row;
            float v0 = 0.f, v1 = 0.f, v2 = 0.f, v3 = 0.f;
            if (grow < n) {
                const float* xp = x + (long)grow * 128 + kp * 64 + c;
                v0 = xp[0]; v1 = xp[16]; v2 = xp[32]; v3 = xp[48];
            }
            As[(c +  0) * 132 + row] = v0;
            As[(c + 16) * 132 + row] = v1;
            As[(c + 32) * 132 + row] = v2;
            As[(c + 48) * 132 + row] = v3;
            float red = (v0 + v1) + (v2 + v3);
            #pragma unroll
            for (int off = 8; off > 0; off >>= 1) red += __shfl_down(red, off, 16);
            if (c == 0) { if (kp == 0) sums[row] = red; else sums[row] += red; }
        }
        #pragma unroll
        for (int i2 = 0; i2 < 4; ++i2) {
            int kk = g + 16 * i2;
            int kglob = kp * 64 + kk;
            float4 wv = *(const float4*)(W1 + (c >> 2) * 2048 + kglob * 16 + 4 * (c & 3));
            *(float4*)(Bs + kk * 64 + 4 * c) = wv;
        }
        __syncthreads();
        #pragma unroll 4
        for (int kk = 0; kk < 64; ++kk) {
            float4 a0 = *(const float4*)(As + kk * 132 + 8 * ty);
            float4 a1 = *(const float4*)(As + kk * 132 + 8 * ty + 4);
            float4 bv = *(const float4*)(Bs + kk * 64 + 4 * tx);
            float ar[8] = {a0.x, a0.y, a0.z, a0.w, a1.x, a1.y, a1.z, a1.w};
            float br[4] = {bv.x, bv.y, bv.z, bv.w};
            #pragma unroll
            for (int i = 0; i < 8; ++i)
                #pragma unroll
                for (int j = 0; j < 4; ++j)
                    acc[i][j] += ar[i] * br[j];
        }
        __syncthreads();
    }
    int plane = tx >> 2;
    int oo4   = 4 * (tx & 3);
    #pragma unroll
    for (int i = 0; i < 8; ++i) {
        int row  = 8 * ty + i;
        int grow = block_row + row;
        if (grow < n) {
            float s = 1.0f / fmaxf(sums[row], 1e-8f);
            float4 o = make_float4(acc[i][0] * s, acc[i][1] * s, acc[i][2] * s, acc[i][3] * s);
            *(float4*)(z + (long)plane * nstride + (long)grow * 16 + oo4) = o;
        }
    }
}
__global__ __launch_bounds__(256) void spmm_atomic_kernel(
    const float* __restrict__ in, float* __restrict__ out,
    const int* __restrict__ src, const int* __restrict__ dst,
    const float* __restrict__ dis, int E)
{
    int t = blockIdx.x * blockDim.x + threadIdx.x;
    int e = t >> 4, f = t & 15;
    if (e < E) {
        int s = src[e], d = dst[e];
        atomicAdd(&out[d * 16 + f], dis[s] * dis[d] * in[s * 16 + f]);
    }
}
__global__ void bias_relu_kernel(float* __restrict__ z0, const float* __restrict__ b, int total) {
    int i = blockIdx.x * blockDim.x + threadIdx.x;
    if (i < total) {
        float v = z0[i] + b[i & 15];
        z0[i] = v > 0.0f ? v : 0.0f;
    }
}
__global__ __launch_bounds__(256) void gemm2_f32_kernel(
    const float* __restrict__ z, const float* __restrict__ W2,
    const float* __restrict__ b2, float* __restrict__ out, int n, int nstride)
{
    __shared__ float As[64 * 132];
    __shared__ float Bs[64 * 64];
    const int t  = threadIdx.x;
    const int tx = t & 15;
    const int ty = t >> 4;
    const int c  = t & 15;
    const int g  = t >> 4;
    const int block_row = blockIdx.x * 128;
    float acc[8][4];
    #pragma unroll
    for (int i = 0; i < 8; ++i)
        #pragma unroll
        for (int j = 0; j < 4; ++j) acc[i][j] = 0.f;
    #pragma unroll
    for (int i = 0; i < 8; ++i) {
        int row  = g + 16 * i;
        int grow = block_row + row;
        float v0 = 0.f, v1 = 0.f, v2 = 0.f, v3 = 0.f;
        if (grow < n) {
            const float* zp = z + (long)grow * 16 + c;
            v0 = zp[0];
            v1 = zp[(long)nstride];
            v2 = zp[2 * (long)nstride];
            v3 = zp[3 * (long)nstride];
        }
        As[(c +  0) * 132 + row] = v0;
        As[(c + 16) * 132 + row] = v1;
        As[(c + 32) * 132 + row] = v2;
        As[(c + 48) * 132 + row] = v3;
    }
    #pragma unroll
    for (int i2 = 0; i2 < 4; ++i2) {
        int j = g + 16 * i2;
        float4 wv = *(const float4*)(W2 + j * 64 + 4 * c);
        *(float4*)(Bs + j * 64 + 4 * c) = wv;
    }
    __syncthreads();
    #pragma unroll 4
    for (int kk = 0; kk < 64; ++kk) {
        float4 a0 = *(const float4*)(As + kk * 132 + 8 * ty);
        float4 a1 = *(const float4*)(As + kk * 132 + 8 * ty + 4);
        float4 bv = *(const float4*)(Bs + kk * 64 + 4 * tx);
        float ar[8] = {a0.x, a0.y, a0.z, a0.w, a1.x, a1.y, a1.z, a1.w};
        float br[4] = {bv.x, bv.y, bv.z, bv.w};
        #pragma unroll
        for (int i = 0; i < 8; ++i)
            #pragma unroll
            for (int j = 0; j < 4; ++j)
                acc[i][j] += ar[i] * br[j];
    }
    float4 bias = *(const float4*)(b2 + 4 * tx);
    #pragma unroll
    for (int i = 0; i < 8; ++i) {
        int grow = block_row + 8 * ty + i;
        if (grow < n) {
            float4 o = make_float4(acc[i][0] + bias.x, acc[i][1] + bias.y,
                                   acc[i][2] + bias.z, acc[i][3] + bias.w);
            *(float4*)(out + (long)grow * 64 + 4 * tx) = o;
        }
    }
}

static inline size_t align16(size_t v) { return (v + 15) & ~(size_t)15; }

extern "C" void kernel_launch(void* const* d_in, const int* in_sizes, int n_in,
                              void* d_out, int out_size, void* d_ws, size_t ws_size,
                              hipStream_t stream) {
    const float* x   = (const float*)d_in[0];
    const int*   ei  = (const int*)d_in[1];
    const float* W1  = (const float*)d_in[2];
    const float* b1  = (const float*)d_in[3];
    const float* W2  = (const float*)d_in[4];
    const float* bb2 = (const float*)d_in[5];
    float* out = (float*)d_out;

    const int n  = in_sizes[0] / 128;   // 50000
    const int E  = in_sizes[1] / 2;     // 800000
    const int NS = n * 16;

    const int* srcp = ei;
    const int* dstp = ei + E;

    char* wsb = (char*)d_ws;
    // layout: bar(16B) | cnt[n] | rowptr[n+1] | cursor[n] | dis[n] | partial[GRID] | zb[6*NS u16] | ecol[E u32]
    int*   bar    = (int*)wsb;
    int*   cnt    = (int*)(wsb + 16);
    int*   rowptr = (int*)(wsb + 16 + (size_t)4 * n);
    int*   cursor = (int*)(wsb + 16 + (size_t)4 * (2 * n + 1));
    float* dis    = (float*)(wsb + 16 + (size_t)4 * (3 * n + 1));
    int*   partial= (int*)(wsb + 16 + (size_t)4 * (4 * n + 1));
    size_t zoffb  = align16(16 + (size_t)4 * (4 * n + 1 + MEGA_GRID));
    u16*   zb     = (u16*)(wsb + zoffb);
    size_t ecooff = align16(zoffb + (size_t)2 * 6 * NS);
    u32*   ecol   = (u32*)(wsb + ecooff);
    size_t need   = ecooff + (size_t)4 * E;

    if (ws_size >= need && n <= MEGA_GRID * 256) {
        // zero bar counter + degree counts, then one persistent kernel for everything
        hipMemsetAsync(wsb, 0, 16 + (size_t)4 * n, stream);
        mega_kernel<<<MEGA_GRID, 256, 0, stream>>>(
            x, srcp, dstp, W1, b1, W2, bb2, out,
            bar, cnt, rowptr, cursor, dis, partial, zb, ecol, n, E, NS);
    } else {
        // ---------- fp32 atomic fallback ----------
        int gemm_blocks = (n + 127) / 128;
        float* ws = (float*)d_ws;
        float* dis2 = ws;
        size_t z2off = ((size_t)n + 3) & ~(size_t)3;
        float* z2 = ws + z2off;
        hipMemsetAsync(dis2, 0, n * sizeof(float), stream);
        deg_kernel<<<(E + 255) / 256, 256, 0, stream>>>(dstp, dis2, E);
        disf_kernel<<<(n + 255) / 256, 256, 0, stream>>>(dis2, n);
        gemm1_f32_kernel<<<gemm_blocks, 256, 0, stream>>>(x, W1, z2, n, NS);
        int sb = (16 * E + 255) / 256;
        spmm_atomic_kernel<<<sb, 256, 0, stream>>>(z2 + 3 * NS, z2 + 2 * NS, srcp, dstp, dis2, E);
        spmm_atomic_kernel<<<sb, 256, 0, stream>>>(z2 + 2 * NS, z2 + 1 * NS, srcp, dstp, dis2, E);
        spmm_atomic_kernel<<<sb, 256, 0, stream>>>(z2 + 1 * NS, z2,          srcp, dstp, dis2, E);
        bias_relu_kernel<<<(NS + 255) / 256, 256, 0, stream>>>(z2, b1, NS);
        hipMemsetAsync(z2 + NS, 0, (size_t)3 * NS * sizeof(float), stream);
        spmm_atomic_kernel<<<sb, 256, 0, stream>>>(z2,          z2 + NS,     srcp, dstp, dis2, E);
        spmm_atomic_kernel<<<sb, 256, 0, stream>>>(z2 + NS,     z2 + 2 * NS, srcp, dstp, dis2, E);
        spmm_atomic_kernel<<<sb, 256, 0, stream>>>(z2 + 2 * NS, z2 + 3 * NS, srcp, dstp, dis2, E);
        gemm2_f32_kernel<<<gemm_blocks, 256, 0, stream>>>(z2, W2, bb2, out, n, NS);
    }
}